// Round 1
// baseline (5019.027 us; speedup 1.0000x reference)
//
#include <hip/hip_runtime.h>
#include <hip/hip_bf16.h>
#include <stdint.h>

#define SEQ   512
#define BATCH 256
#define EMBD  256
#define HID   512
#define OUTD  4

typedef float  f32x4 __attribute__((ext_vector_type(4)));
typedef short  s16x8 __attribute__((ext_vector_type(8)));
typedef __bf16 bf16x8 __attribute__((ext_vector_type(8)));

static __device__ __forceinline__ short f2bf(float f) {
    union { float f; uint32_t u; } v; v.f = f;
    uint32_t u = v.u;
    u += 0x7fffu + ((u >> 16) & 1u);      // round-to-nearest-even
    return (short)(u >> 16);
}
static __device__ __forceinline__ float bf2f(short s) {
    union { uint32_t u; float f; } v;
    v.u = ((uint32_t)(uint16_t)s) << 16;
    return v.f;
}

static __device__ __forceinline__ f32x4 mfma_bf16(s16x8 a, s16x8 b, f32x4 c) {
    return __builtin_amdgcn_mfma_f32_16x16x32_bf16(
        __builtin_bit_cast(bf16x8, a), __builtin_bit_cast(bf16x8, b), c, 0, 0, 0);
}

// xp store/load: f32 or bf16 (workspace-size dependent)
static __device__ __forceinline__ void  xp_store(float* p, float v) { *p = v; }
static __device__ __forceinline__ void  xp_store(short* p, float v) { *p = f2bf(v); }
static __device__ __forceinline__ float xp_load(const float* p)     { return *p; }
static __device__ __forceinline__ float xp_load(const short* p)     { return bf2f(*p); }

// ---------------------------------------------------------------------------
// Kernel 1: xp[s,b,h] = emb[text[s,b],:] @ W_ih[h,:] + b_ih[h] + b_hh[h]
// Tile: 128 rows (flattened s*B+b) x 128 cols, K = EMBD = 256 single pass.
// LDS: A-tile 128x256 bf16 (64KB, XOR-swizzled) + B-tile 128x256 bf16 (64KB).
// ---------------------------------------------------------------------------
template <typename XT>
__global__ __launch_bounds__(512, 1)
void xproj_kernel(const int* __restrict__ text, const float* __restrict__ emb,
                  const float* __restrict__ W_ih, const float* __restrict__ b_ih,
                  const float* __restrict__ b_hh, XT* __restrict__ xp) {
    extern __shared__ char lds[];
    char* As = lds;             // [128][256] bf16, swizzled
    char* Bs = lds + 65536;     // [128][256] bf16, swizzled

    const int t    = threadIdx.x;
    const int row0 = blockIdx.x * 128;   // flattened S*B row
    const int col0 = blockIdx.y * 128;   // H col

    // ---- stage A: gathered embedding rows, f32 -> bf16 ----
    {
        const int r   = t >> 2;            // 0..127
        const int kc  = (t & 3) * 64;      // 0,64,128,192
        const int tok = text[row0 + r];
        const float* src = emb + (size_t)tok * EMBD + kc;
        #pragma unroll
        for (int u = 0; u < 64; u += 8) {
            f32x4 x0 = *(const f32x4*)(src + u);
            f32x4 x1 = *(const f32x4*)(src + u + 4);
            s16x8 pk;
            pk[0]=f2bf(x0.x); pk[1]=f2bf(x0.y); pk[2]=f2bf(x0.z); pk[3]=f2bf(x0.w);
            pk[4]=f2bf(x1.x); pk[5]=f2bf(x1.y); pk[6]=f2bf(x1.z); pk[7]=f2bf(x1.w);
            int byte = (r * 512 + (kc + u) * 2) ^ ((r & 7) << 4);
            *(s16x8*)(As + byte) = pk;
        }
    }
    // ---- stage B: W_ih slice [col0..col0+127][0..255], f32 -> bf16 ----
    {
        const int c  = t >> 2;
        const int kc = (t & 3) * 64;
        const float* src = W_ih + (size_t)(col0 + c) * EMBD + kc;
        #pragma unroll
        for (int u = 0; u < 64; u += 8) {
            f32x4 x0 = *(const f32x4*)(src + u);
            f32x4 x1 = *(const f32x4*)(src + u + 4);
            s16x8 pk;
            pk[0]=f2bf(x0.x); pk[1]=f2bf(x0.y); pk[2]=f2bf(x0.z); pk[3]=f2bf(x0.w);
            pk[4]=f2bf(x1.x); pk[5]=f2bf(x1.y); pk[6]=f2bf(x1.z); pk[7]=f2bf(x1.w);
            int byte = (c * 512 + (kc + u) * 2) ^ ((c & 7) << 4);
            *(s16x8*)(Bs + byte) = pk;
        }
    }
    __syncthreads();

    // ---- MFMA: 8 waves = 2(M) x 4(N); wave tile 64 rows x 32 cols ----
    const int lane = t & 63;
    const int w    = t >> 6;
    const int wm   = w >> 2;            // 0..1
    const int wn   = w & 3;             // 0..3
    const int lr   = lane & 15;
    const int lk   = (lane >> 4) * 8;   // k element offset within 32-chunk

    f32x4 acc[4][2] = {};
    #pragma unroll
    for (int kk = 0; kk < 8; ++kk) {
        s16x8 a[4], b[2];
        #pragma unroll
        for (int mt = 0; mt < 4; ++mt) {
            int r = wm * 64 + mt * 16 + lr;
            int byte = (r * 512 + (kk * 32 + lk) * 2) ^ ((r & 7) << 4);
            a[mt] = *(const s16x8*)(As + byte);
        }
        #pragma unroll
        for (int nt = 0; nt < 2; ++nt) {
            int c = wn * 32 + nt * 16 + lr;
            int byte = (c * 512 + (kk * 32 + lk) * 2) ^ ((c & 7) << 4);
            b[nt] = *(const s16x8*)(Bs + byte);
        }
        #pragma unroll
        for (int mt = 0; mt < 4; ++mt)
            #pragma unroll
            for (int nt = 0; nt < 2; ++nt)
                acc[mt][nt] = mfma_bf16(a[mt], b[nt], acc[mt][nt]);
    }

    // ---- epilogue: + (b_ih + b_hh), store xp ----
    #pragma unroll
    for (int nt = 0; nt < 2; ++nt) {
        const int c = col0 + wn * 32 + nt * 16 + lr;
        const float bias = b_ih[c] + b_hh[c];
        #pragma unroll
        for (int mt = 0; mt < 4; ++mt) {
            #pragma unroll
            for (int r4 = 0; r4 < 4; ++r4) {
                const int rr = row0 + wm * 64 + mt * 16 + (lane >> 4) * 4 + r4;
                xp_store(xp + (size_t)rr * HID + c, acc[mt][nt][r4] + bias);
            }
        }
    }
}

// ---------------------------------------------------------------------------
// Kernel 2: recurrence h = tanh(xp[s] + h @ W_hh^T), then FC head.
// 64 WGs (1/CU): group gi (16 batch rows) x slice gj (128 H cols).
// W_hh slice [128 cols][512 k] bf16 LDS-resident (128KB, XOR-swizzled).
// Per step: 4-WG group barrier (agent-scope atomics + fences), double-buffered
// h (bf16) in workspace. Group members share an XCD via bid remap.
// ---------------------------------------------------------------------------
template <typename XT>
__global__ __launch_bounds__(256, 1)
void rnn_kernel(const float* __restrict__ W_hh, const XT* __restrict__ xp,
                const float* __restrict__ fc_w, const float* __restrict__ fc_b,
                short* __restrict__ hbuf, unsigned int* __restrict__ bar,
                float* __restrict__ out) {
    extern __shared__ char lds[];   // W slice [128][512] bf16 swizzled

    const int bid  = blockIdx.x;                       // 0..63
    const int gi   = (bid & 7) + ((bid >> 5) << 3);    // row group 0..15 (same XCD per group)
    const int gj   = (bid >> 3) & 3;                   // col slice 0..3
    const int t    = threadIdx.x;
    const int lane = t & 63;
    const int w    = t >> 6;                           // 0..3 waves
    const int row0 = gi * 16;
    const int col0 = gj * 128;

    // ---- stage W_hh slice (once): rows col0..col0+127 of W_hh, f32 -> bf16 ----
    {
        const int c  = t >> 1;              // 0..127
        const int k0 = (t & 1) * 256;
        const float* src = W_hh + (size_t)(col0 + c) * HID + k0;
        #pragma unroll 4
        for (int u = 0; u < 256; u += 8) {
            f32x4 x0 = *(const f32x4*)(src + u);
            f32x4 x1 = *(const f32x4*)(src + u + 4);
            s16x8 pk;
            pk[0]=f2bf(x0.x); pk[1]=f2bf(x0.y); pk[2]=f2bf(x0.z); pk[3]=f2bf(x0.w);
            pk[4]=f2bf(x1.x); pk[5]=f2bf(x1.y); pk[6]=f2bf(x1.z); pk[7]=f2bf(x1.w);
            int byte = (c * 1024 + (k0 + u) * 2) ^ ((c & 7) << 4);
            *(s16x8*)(lds + byte) = pk;
        }
    }
    __syncthreads();

    const int lr    = lane & 15;
    const int lkb   = (lane >> 4) * 16;         // byte offset of lane's 8 bf16
    const int arow  = row0 + lr;                // A-fragment row (global batch row)
    const int crow0 = row0 + (lane >> 4) * 4;   // C row base
    unsigned int* mybar = bar + gi;

    int p = 0;
    for (int s = 0; s < SEQ; ++s) {
        // xp -> accumulator init (independent of h: issue before the spin)
        f32x4 acc[2];
        #pragma unroll
        for (int nt = 0; nt < 2; ++nt) {
            const int c = col0 + w * 32 + nt * 16 + lr;
            const XT* xs = xp + ((size_t)s * BATCH + crow0) * HID + c;
            #pragma unroll
            for (int r = 0; r < 4; ++r) acc[nt][r] = xp_load(xs + (size_t)r * HID);
        }

        // wait for previous step's h from the other 3 WGs of this group
        if (s > 0) {
            if (t == 0) {
                const unsigned int target = 4u * (unsigned int)s;
                int guard = 0;
                while (__hip_atomic_load(mybar, __ATOMIC_RELAXED,
                                         __HIP_MEMORY_SCOPE_AGENT) < target) {
                    __builtin_amdgcn_s_sleep(2);
                    if (++guard > (1 << 27)) break;   // safety valve: no hang
                }
            }
            __syncthreads();
            __builtin_amdgcn_fence(__ATOMIC_ACQUIRE, "agent");
        }

        // h @ W_slice^T : A-frags direct from global h, B-frags from LDS
        const short* hb   = hbuf + (size_t)p * (BATCH * HID);
        const char*  hrow = (const char*)(hb + (size_t)arow * HID);
        const int cl0 = w * 32 + lr;
        const int cl1 = cl0 + 16;
        #pragma unroll
        for (int kk = 0; kk < 16; ++kk) {
            const s16x8 a   = *(const s16x8*)(hrow + kk * 64 + lkb);
            const int b0b = (cl0 * 1024 + kk * 64 + lkb) ^ ((cl0 & 7) << 4);
            const int b1b = (cl1 * 1024 + kk * 64 + lkb) ^ ((cl1 & 7) << 4);
            const s16x8 b0v = *(const s16x8*)(lds + b0b);
            const s16x8 b1v = *(const s16x8*)(lds + b1b);
            acc[0] = mfma_bf16(a, b0v, acc[0]);
            acc[1] = mfma_bf16(a, b1v, acc[1]);
        }

        // tanh + store h_new (bf16) into the other buffer
        short* hn = hbuf + (size_t)(p ^ 1) * (BATCH * HID);
        #pragma unroll
        for (int nt = 0; nt < 2; ++nt) {
            const int c = col0 + w * 32 + nt * 16 + lr;
            #pragma unroll
            for (int r = 0; r < 4; ++r) {
                const float hv = tanhf(acc[nt][r]);
                hn[(size_t)(crow0 + r) * HID + c] = f2bf(hv);
            }
        }

        __builtin_amdgcn_fence(__ATOMIC_RELEASE, "agent");
        __syncthreads();
        if (t == 0)
            __hip_atomic_fetch_add(mybar, 1u, __ATOMIC_RELAXED,
                                   __HIP_MEMORY_SCOPE_AGENT);
        p ^= 1;
    }

    // ---- FC head: one WG per row group computes out[rows, 0..3] ----
    if (gj == 0) {
        if (t == 0) {
            int guard = 0;
            while (__hip_atomic_load(mybar, __ATOMIC_RELAXED,
                                     __HIP_MEMORY_SCOPE_AGENT) < 4u * SEQ) {
                __builtin_amdgcn_s_sleep(2);
                if (++guard > (1 << 27)) break;
            }
        }
        __syncthreads();
        __builtin_amdgcn_fence(__ATOMIC_ACQUIRE, "agent");
        if (t < 64) {
            const int b = row0 + (t >> 2);
            const int o = t & 3;
            const short* hb = hbuf + (size_t)p * (BATCH * HID) + (size_t)b * HID;
            float sum = fc_b[o];
            for (int k = 0; k < HID; ++k)
                sum += bf2f(hb[k]) * fc_w[o * HID + k];
            out[b * OUTD + o] = sum;
        }
    }
}

// ---------------------------------------------------------------------------
extern "C" void kernel_launch(void* const* d_in, const int* in_sizes, int n_in,
                              void* d_out, int out_size, void* d_ws, size_t ws_size,
                              hipStream_t stream) {
    (void)in_sizes; (void)n_in; (void)out_size;
    const int*   text = (const int*)  d_in[0];
    const float* emb  = (const float*)d_in[1];
    const float* W_ih = (const float*)d_in[2];
    const float* W_hh = (const float*)d_in[3];
    const float* b_ih = (const float*)d_in[4];
    const float* b_hh = (const float*)d_in[5];
    const float* fc_w = (const float*)d_in[6];
    const float* fc_b = (const float*)d_in[7];
    float* out = (float*)d_out;

    char* ws = (char*)d_ws;
    short*        hbuf = (short*)ws;                        // 2*256*512*2 = 512 KB
    unsigned int* bar  = (unsigned int*)(ws + (512 << 10)); // 16 counters
    void*         xpbf = (void*)(ws + (1 << 20));

    const size_t base     = (size_t)1 << 20;
    const size_t xp_elems = (size_t)SEQ * BATCH * HID;
    const bool use_f32  = ws_size >= base + xp_elems * 4;
    const bool use_bf16 = !use_f32 && ws_size >= base + xp_elems * 2;

    // zero h0 + barrier counters (must happen every call: deterministic)
    hipMemsetAsync(ws, 0, (512 << 10) + 4096, stream);

    if (use_f32) {
        hipFuncSetAttribute(reinterpret_cast<const void*>(&xproj_kernel<float>),
                            hipFuncAttributeMaxDynamicSharedMemorySize, 131072);
        hipFuncSetAttribute(reinterpret_cast<const void*>(&rnn_kernel<float>),
                            hipFuncAttributeMaxDynamicSharedMemorySize, 131072);
        xproj_kernel<float><<<dim3(1024, 4, 1), 512, 131072, stream>>>(
            text, emb, W_ih, b_ih, b_hh, (float*)xpbf);
        rnn_kernel<float><<<64, 256, 131072, stream>>>(
            W_hh, (const float*)xpbf, fc_w, fc_b, hbuf, bar, out);
    } else if (use_bf16) {
        hipFuncSetAttribute(reinterpret_cast<const void*>(&xproj_kernel<short>),
                            hipFuncAttributeMaxDynamicSharedMemorySize, 131072);
        hipFuncSetAttribute(reinterpret_cast<const void*>(&rnn_kernel<short>),
                            hipFuncAttributeMaxDynamicSharedMemorySize, 131072);
        xproj_kernel<short><<<dim3(1024, 4, 1), 512, 131072, stream>>>(
            text, emb, W_ih, b_ih, b_hh, (short*)xpbf);
        rnn_kernel<short><<<64, 256, 131072, stream>>>(
            W_hh, (const short*)xpbf, fc_w, fc_b, hbuf, bar, out);
    }
    // else: workspace too small for any path — no launch (signals via bench).
}

// Round 2
// 2305.238 us; speedup vs baseline: 2.1772x; 2.1772x over previous
//
#include <hip/hip_runtime.h>
#include <hip/hip_bf16.h>
#include <stdint.h>

#define SEQ   512
#define BATCH 256
#define EMBD  256
#define HID   512
#define OUTD  4

typedef float  f32x4 __attribute__((ext_vector_type(4)));
typedef short  s16x8 __attribute__((ext_vector_type(8)));
typedef __bf16 bf16x8 __attribute__((ext_vector_type(8)));

static __device__ __forceinline__ short f2bf(float f) {
    union { float f; uint32_t u; } v; v.f = f;
    uint32_t u = v.u;
    u += 0x7fffu + ((u >> 16) & 1u);      // round-to-nearest-even
    return (short)(u >> 16);
}
static __device__ __forceinline__ float bf2f(short s) {
    union { uint32_t u; float f; } v;
    v.u = ((uint32_t)(uint16_t)s) << 16;
    return v.f;
}

static __device__ __forceinline__ f32x4 mfma_bf16(s16x8 a, s16x8 b, f32x4 c) {
    return __builtin_amdgcn_mfma_f32_16x16x32_bf16(
        __builtin_bit_cast(bf16x8, a), __builtin_bit_cast(bf16x8, b), c, 0, 0, 0);
}

// Agent-coherent (L1/L2-bypassing) accesses: data goes to/from the L3
// coherence point directly, so NO acquire/release fences (wbl2/inv) needed.
static __device__ __forceinline__ s16x8 load_coherent_b128(const void* p) {
    s16x8 r;
    asm volatile("global_load_dwordx4 %0, %1, off sc0 sc1"
                 : "=v"(r) : "v"(p) : "memory");
    return r;
}
static __device__ __forceinline__ void store_coherent_b128(void* p, s16x8 v) {
    asm volatile("global_store_dwordx4 %0, %1, off sc0 sc1"
                 :: "v"(p), "v"(v) : "memory");
}
static __device__ __forceinline__ void wait_vm0() {
    asm volatile("s_waitcnt vmcnt(0)" ::: "memory");
    __builtin_amdgcn_sched_barrier(0);   // rule #18: keep MFMA after the wait
}

// xp store/load: f32 or bf16 (workspace-size dependent)
static __device__ __forceinline__ void  xp_store(float* p, float v) { *p = v; }
static __device__ __forceinline__ void  xp_store(short* p, float v) { *p = f2bf(v); }
static __device__ __forceinline__ float xp_load(const float* p)     { return *p; }
static __device__ __forceinline__ float xp_load(const short* p)     { return bf2f(*p); }

// ---------------------------------------------------------------------------
// Kernel 1: xp[s,b,h] = emb[text[s,b],:] @ W_ih[h,:] + b_ih[h] + b_hh[h]
// ---------------------------------------------------------------------------
template <typename XT>
__global__ __launch_bounds__(512, 1)
void xproj_kernel(const int* __restrict__ text, const float* __restrict__ emb,
                  const float* __restrict__ W_ih, const float* __restrict__ b_ih,
                  const float* __restrict__ b_hh, XT* __restrict__ xp) {
    extern __shared__ char lds[];
    char* As = lds;             // [128][256] bf16, swizzled
    char* Bs = lds + 65536;     // [128][256] bf16, swizzled

    const int t    = threadIdx.x;
    const int row0 = blockIdx.x * 128;   // flattened S*B row
    const int col0 = blockIdx.y * 128;   // H col

    {   // stage A: gathered embedding rows, f32 -> bf16
        const int r   = t >> 2;
        const int kc  = (t & 3) * 64;
        const int tok = text[row0 + r];
        const float* src = emb + (size_t)tok * EMBD + kc;
        #pragma unroll
        for (int u = 0; u < 64; u += 8) {
            f32x4 x0 = *(const f32x4*)(src + u);
            f32x4 x1 = *(const f32x4*)(src + u + 4);
            s16x8 pk;
            pk[0]=f2bf(x0.x); pk[1]=f2bf(x0.y); pk[2]=f2bf(x0.z); pk[3]=f2bf(x0.w);
            pk[4]=f2bf(x1.x); pk[5]=f2bf(x1.y); pk[6]=f2bf(x1.z); pk[7]=f2bf(x1.w);
            int byte = (r * 512 + (kc + u) * 2) ^ ((r & 7) << 4);
            *(s16x8*)(As + byte) = pk;
        }
    }
    {   // stage B: W_ih slice
        const int c  = t >> 2;
        const int kc = (t & 3) * 64;
        const float* src = W_ih + (size_t)(col0 + c) * EMBD + kc;
        #pragma unroll
        for (int u = 0; u < 64; u += 8) {
            f32x4 x0 = *(const f32x4*)(src + u);
            f32x4 x1 = *(const f32x4*)(src + u + 4);
            s16x8 pk;
            pk[0]=f2bf(x0.x); pk[1]=f2bf(x0.y); pk[2]=f2bf(x0.z); pk[3]=f2bf(x0.w);
            pk[4]=f2bf(x1.x); pk[5]=f2bf(x1.y); pk[6]=f2bf(x1.z); pk[7]=f2bf(x1.w);
            int byte = (c * 512 + (kc + u) * 2) ^ ((c & 7) << 4);
            *(s16x8*)(Bs + byte) = pk;
        }
    }
    __syncthreads();

    const int lane = t & 63;
    const int w    = t >> 6;
    const int wm   = w >> 2;
    const int wn   = w & 3;
    const int lr   = lane & 15;
    const int lk   = (lane >> 4) * 8;

    f32x4 acc[4][2] = {};
    #pragma unroll
    for (int kk = 0; kk < 8; ++kk) {
        s16x8 a[4], b[2];
        #pragma unroll
        for (int mt = 0; mt < 4; ++mt) {
            int r = wm * 64 + mt * 16 + lr;
            int byte = (r * 512 + (kk * 32 + lk) * 2) ^ ((r & 7) << 4);
            a[mt] = *(const s16x8*)(As + byte);
        }
        #pragma unroll
        for (int nt = 0; nt < 2; ++nt) {
            int c = wn * 32 + nt * 16 + lr;
            int byte = (c * 512 + (kk * 32 + lk) * 2) ^ ((c & 7) << 4);
            b[nt] = *(const s16x8*)(Bs + byte);
        }
        #pragma unroll
        for (int mt = 0; mt < 4; ++mt)
            #pragma unroll
            for (int nt = 0; nt < 2; ++nt)
                acc[mt][nt] = mfma_bf16(a[mt], b[nt], acc[mt][nt]);
    }

    #pragma unroll
    for (int nt = 0; nt < 2; ++nt) {
        const int c = col0 + wn * 32 + nt * 16 + lr;
        const float bias = b_ih[c] + b_hh[c];
        #pragma unroll
        for (int mt = 0; mt < 4; ++mt) {
            #pragma unroll
            for (int r4 = 0; r4 < 4; ++r4) {
                const int rr = row0 + wm * 64 + mt * 16 + (lane >> 4) * 4 + r4;
                xp_store(xp + (size_t)rr * HID + c, acc[mt][nt][r4] + bias);
            }
        }
    }
}

// ---------------------------------------------------------------------------
// Kernel 2: recurrence h = tanh(xp[s] + h @ W_hh^T), then FC head.
// 64 WGs: group gi (16 batch rows) x slice gj (128 H cols). W_hh slice
// LDS-resident (128KB). Cross-WG h exchange via cache-bypassing (sc0 sc1)
// loads/stores + relaxed agent atomics — NO fences, NO L2 wb/inv per step.
// ---------------------------------------------------------------------------
template <typename XT>
__global__ __launch_bounds__(256, 1)
void rnn_kernel(const float* __restrict__ W_hh, const XT* __restrict__ xp,
                const float* __restrict__ fc_w, const float* __restrict__ fc_b,
                short* __restrict__ hbuf, unsigned int* __restrict__ bar,
                float* __restrict__ out) {
    extern __shared__ char lds[];                 // W slice [128][512] bf16 swizzled
    short* hstage = (short*)(lds + 131072);       // [16][128] bf16 transpose buffer

    const int bid  = blockIdx.x;                       // 0..63
    const int gi   = (bid & 7) + ((bid >> 5) << 3);    // row group 0..15
    const int gj   = (bid >> 3) & 3;                   // col slice 0..3
    const int t    = threadIdx.x;
    const int lane = t & 63;
    const int w    = t >> 6;                           // 0..3 waves
    const int row0 = gi * 16;
    const int col0 = gj * 128;

    {   // stage W_hh slice (once), f32 -> bf16
        const int c  = t >> 1;
        const int k0 = (t & 1) * 256;
        const float* src = W_hh + (size_t)(col0 + c) * HID + k0;
        #pragma unroll 4
        for (int u = 0; u < 256; u += 8) {
            f32x4 x0 = *(const f32x4*)(src + u);
            f32x4 x1 = *(const f32x4*)(src + u + 4);
            s16x8 pk;
            pk[0]=f2bf(x0.x); pk[1]=f2bf(x0.y); pk[2]=f2bf(x0.z); pk[3]=f2bf(x0.w);
            pk[4]=f2bf(x1.x); pk[5]=f2bf(x1.y); pk[6]=f2bf(x1.z); pk[7]=f2bf(x1.w);
            int byte = (c * 1024 + (k0 + u) * 2) ^ ((c & 7) << 4);
            *(s16x8*)(lds + byte) = pk;
        }
    }
    __syncthreads();

    const int lr    = lane & 15;
    const int lkb   = (lane >> 4) * 16;         // byte offset of lane's 8 bf16
    const int arow  = row0 + lr;                // A-fragment row
    const int crow0 = row0 + (lane >> 4) * 4;   // C row base
    unsigned int* mybar = bar + gi;

    int p = 0;
    for (int s = 0; s < SEQ; ++s) {
        // xp -> accumulator init (plain cached loads; independent of h)
        f32x4 acc[2];
        #pragma unroll
        for (int nt = 0; nt < 2; ++nt) {
            const int c = col0 + w * 32 + nt * 16 + lr;
            const XT* xs = xp + ((size_t)s * BATCH + crow0) * HID + c;
            #pragma unroll
            for (int r = 0; r < 4; ++r) acc[nt][r] = xp_load(xs + (size_t)r * HID);
        }

        // wait for previous step's h from the other WGs of this group
        if (s > 0) {
            if (t == 0) {
                const unsigned int target = 4u * (unsigned int)s;
                int guard = 0;
                while (__hip_atomic_load(mybar, __ATOMIC_RELAXED,
                                         __HIP_MEMORY_SCOPE_AGENT) < target) {
                    __builtin_amdgcn_s_sleep(1);
                    if (++guard > (1 << 27)) break;   // safety valve
                }
            }
            __syncthreads();
        }

        // A-fragments: coherent (bypass) loads of this lane's h row
        const short* hb   = hbuf + (size_t)p * (BATCH * HID);
        const char*  hrow = (const char*)(hb + (size_t)arow * HID);
        s16x8 areg[16];
        #pragma unroll
        for (int kk = 0; kk < 16; ++kk)
            areg[kk] = load_coherent_b128(hrow + kk * 64 + lkb);
        wait_vm0();

        const int cl0 = w * 32 + lr;
        const int cl1 = cl0 + 16;
        #pragma unroll
        for (int kk = 0; kk < 16; ++kk) {
            const int b0b = (cl0 * 1024 + kk * 64 + lkb) ^ ((cl0 & 7) << 4);
            const int b1b = (cl1 * 1024 + kk * 64 + lkb) ^ ((cl1 & 7) << 4);
            const s16x8 b0v = *(const s16x8*)(lds + b0b);
            const s16x8 b1v = *(const s16x8*)(lds + b1b);
            acc[0] = mfma_bf16(areg[kk], b0v, acc[0]);
            acc[1] = mfma_bf16(areg[kk], b1v, acc[1]);
        }

        // tanh -> LDS transpose stage (row-major [16][128])
        #pragma unroll
        for (int nt = 0; nt < 2; ++nt) {
            const int cl = w * 32 + nt * 16 + lr;
            #pragma unroll
            for (int r = 0; r < 4; ++r)
                hstage[((crow0 - row0) + r) * 128 + cl] = f2bf(tanhf(acc[nt][r]));
        }
        __syncthreads();   // hstage complete

        // vectorized coherent store: thread t -> row t>>4, col8 (t&15)*8
        {
            const int rr = t >> 4, c8 = (t & 15) * 8;
            s16x8 v = *(const s16x8*)(hstage + rr * 128 + c8);
            short* hn = hbuf + (size_t)(p ^ 1) * (BATCH * HID)
                             + (size_t)(row0 + rr) * HID + (col0 + c8);
            store_coherent_b128(hn, v);
        }
        __syncthreads();   // implicit per-wave vmcnt(0) drain -> stores visible

        if (t == 0)
            __hip_atomic_fetch_add(mybar, 1u, __ATOMIC_RELAXED,
                                   __HIP_MEMORY_SCOPE_AGENT);
        p ^= 1;
    }

    // ---- FC head: WGs with gj==0 compute out[rows, 0..3] ----
    if (gj == 0) {
        if (t == 0) {
            int guard = 0;
            while (__hip_atomic_load(mybar, __ATOMIC_RELAXED,
                                     __HIP_MEMORY_SCOPE_AGENT) < 4u * SEQ) {
                __builtin_amdgcn_s_sleep(1);
                if (++guard > (1 << 27)) break;
            }
        }
        __syncthreads();

        // 256 threads: (b_local, o) pairs x 4 k-quarters, shuffle-reduced
        const int i  = t >> 2;        // 0..63
        const int q  = t & 3;         // k quarter
        const int bl = i >> 2;        // 0..15 batch row local
        const int o  = i & 3;         // output idx
        const short* hb = hbuf + (size_t)p * (BATCH * HID)
                               + (size_t)(row0 + bl) * HID + q * 128;
        s16x8 hv[16];
        #pragma unroll
        for (int kk = 0; kk < 16; ++kk)
            hv[kk] = load_coherent_b128((const char*)hb + kk * 16);
        wait_vm0();
        float sum = 0.f;
        #pragma unroll
        for (int kk = 0; kk < 16; ++kk)
            #pragma unroll
            for (int j = 0; j < 8; ++j)
                sum += bf2f(hv[kk][j]) * fc_w[o * HID + q * 128 + kk * 8 + j];
        sum += __shfl_xor(sum, 1);
        sum += __shfl_xor(sum, 2);
        if (q == 0)
            out[(row0 + bl) * OUTD + o] = sum + fc_b[o];
    }
}

// ---------------------------------------------------------------------------
extern "C" void kernel_launch(void* const* d_in, const int* in_sizes, int n_in,
                              void* d_out, int out_size, void* d_ws, size_t ws_size,
                              hipStream_t stream) {
    (void)in_sizes; (void)n_in; (void)out_size;
    const int*   text = (const int*)  d_in[0];
    const float* emb  = (const float*)d_in[1];
    const float* W_ih = (const float*)d_in[2];
    const float* W_hh = (const float*)d_in[3];
    const float* b_ih = (const float*)d_in[4];
    const float* b_hh = (const float*)d_in[5];
    const float* fc_w = (const float*)d_in[6];
    const float* fc_b = (const float*)d_in[7];
    float* out = (float*)d_out;

    char* ws = (char*)d_ws;
    short*        hbuf = (short*)ws;                        // 2*256*512*2 = 512 KB
    unsigned int* bar  = (unsigned int*)(ws + (512 << 10)); // 16 counters
    void*         xpbf = (void*)(ws + (1 << 20));

    const size_t base     = (size_t)1 << 20;
    const size_t xp_elems = (size_t)SEQ * BATCH * HID;
    const bool use_f32  = ws_size >= base + xp_elems * 4;
    const bool use_bf16 = !use_f32 && ws_size >= base + xp_elems * 2;

    // zero h0 + barrier counters (every call: deterministic)
    hipMemsetAsync(ws, 0, (512 << 10) + 4096, stream);

    if (use_f32) {
        hipFuncSetAttribute(reinterpret_cast<const void*>(&xproj_kernel<float>),
                            hipFuncAttributeMaxDynamicSharedMemorySize, 131072);
        hipFuncSetAttribute(reinterpret_cast<const void*>(&rnn_kernel<float>),
                            hipFuncAttributeMaxDynamicSharedMemorySize, 135168);
        xproj_kernel<float><<<dim3(1024, 4, 1), 512, 131072, stream>>>(
            text, emb, W_ih, b_ih, b_hh, (float*)xpbf);
        rnn_kernel<float><<<64, 256, 135168, stream>>>(
            W_hh, (const float*)xpbf, fc_w, fc_b, hbuf, bar, out);
    } else if (use_bf16) {
        hipFuncSetAttribute(reinterpret_cast<const void*>(&xproj_kernel<short>),
                            hipFuncAttributeMaxDynamicSharedMemorySize, 131072);
        hipFuncSetAttribute(reinterpret_cast<const void*>(&rnn_kernel<short>),
                            hipFuncAttributeMaxDynamicSharedMemorySize, 135168);
        xproj_kernel<short><<<dim3(1024, 4, 1), 512, 131072, stream>>>(
            text, emb, W_ih, b_ih, b_hh, (short*)xpbf);
        rnn_kernel<short><<<64, 256, 135168, stream>>>(
            W_hh, (const short*)xpbf, fc_w, fc_b, hbuf, bar, out);
    }
    // else: workspace too small — no launch (signals via bench).
}